// Round 1
// baseline (30526.636 us; speedup 1.0000x reference)
//
#include <hip/hip_runtime.h>
#include <math.h>

// GRU encoder: B=512, T=128, V=128, E=512, H=512, L=2
// d_out layout: states[T][L][B][H] (f32) followed by h_final[L][B][H] (f32).
// Round 1: correctness-first fused per-step f32 kernel.
//   - one launch per (layer, t): 256 launches, stream-ordered (recurrence).
//   - each launch: tiled GEMM over K=1024 (x-phase K=512 + h-phase K=512),
//     32x32 output tile per 256-thread block, gate math fused in epilogue.
//   - h_prev read from d_out (states[t-1]) -> no workspace needed.

#define BB 512
#define TT 128
#define VV 128
#define EE 512
#define HH 512
#define LL 2

#define TB 32   // batch tile
#define TH 32   // h tile
#define TK 16   // k tile

__device__ __forceinline__ float sigmoidf_(float x) {
    return 1.0f / (1.0f + expf(-x));
}

__global__ __launch_bounds__(256) void gru_step(
    const int*   __restrict__ input,   // [B,T]
    const float* __restrict__ emb,     // [V,E]
    const float* __restrict__ h0,      // [L,B,H]
    const float* __restrict__ w_ih,    // [L,3H,E]
    const float* __restrict__ w_hh,    // [L,3H,H]
    const float* __restrict__ b_ih,    // [L,3H]
    const float* __restrict__ b_hh,    // [L,3H]
    float*       __restrict__ out,     // [T,L,B,H]
    int layer, int t)
{
    const int bb0 = blockIdx.x * TB;
    const int hh0 = blockIdx.y * TH;
    const int tid = threadIdx.x;
    const int tx  = tid & 15;   // h within tile (plus +16)
    const int ty  = tid >> 4;   // b within tile (plus +16)

    __shared__ const float* Xrow[TB];
    __shared__ const float* Hrow[TB];
    __shared__ float Xs[TK][TB + 1];
    __shared__ float Ws[3][TK][TH + 1];

    if (tid < TB) {
        const int b = bb0 + tid;
        if (layer == 0) {
            const int idx = input[b * TT + t];
            Xrow[tid] = emb + (size_t)idx * EE;
        } else {
            // layer-1 input = layer-0 state at same t
            Xrow[tid] = out + ((size_t)(t * LL + 0) * BB + b) * HH;
        }
        if (t == 0) {
            Hrow[tid] = h0 + ((size_t)layer * BB + b) * HH;
        } else {
            Hrow[tid] = out + ((size_t)((t - 1) * LL + layer) * BB + b) * HH;
        }
    }
    __syncthreads();

    float acc_r[2][2]  = {{0.f,0.f},{0.f,0.f}};
    float acc_z[2][2]  = {{0.f,0.f},{0.f,0.f}};
    float acc_in[2][2] = {{0.f,0.f},{0.f,0.f}};
    float acc_hn[2][2] = {{0.f,0.f},{0.f,0.f}};

    const float* Wi = w_ih + (size_t)layer * 3 * HH * EE;
    const float* Wh = w_hh + (size_t)layer * 3 * HH * HH;

    // ---- phase 0: x @ w_ih^T ----
    for (int k0 = 0; k0 < EE; k0 += TK) {
        __syncthreads();
        #pragma unroll
        for (int e = tid; e < TB * TK; e += 256) {
            const int b = e >> 4, k = e & 15;
            Xs[k][b] = Xrow[b][k0 + k];
        }
        #pragma unroll
        for (int e = tid; e < 3 * TH * TK; e += 256) {
            const int g = e >> 9, rem = e & 511;
            const int h = rem >> 4, k = rem & 15;
            Ws[g][k][h] = Wi[((size_t)(g * HH + hh0 + h)) * EE + k0 + k];
        }
        __syncthreads();
        #pragma unroll
        for (int kk = 0; kk < TK; ++kk) {
            const float xv0 = Xs[kk][ty];
            const float xv1 = Xs[kk][ty + 16];
            const float wr0 = Ws[0][kk][tx], wr1 = Ws[0][kk][tx + 16];
            const float wz0 = Ws[1][kk][tx], wz1 = Ws[1][kk][tx + 16];
            const float wn0 = Ws[2][kk][tx], wn1 = Ws[2][kk][tx + 16];
            acc_r[0][0]  += xv0 * wr0; acc_r[0][1]  += xv0 * wr1;
            acc_r[1][0]  += xv1 * wr0; acc_r[1][1]  += xv1 * wr1;
            acc_z[0][0]  += xv0 * wz0; acc_z[0][1]  += xv0 * wz1;
            acc_z[1][0]  += xv1 * wz0; acc_z[1][1]  += xv1 * wz1;
            acc_in[0][0] += xv0 * wn0; acc_in[0][1] += xv0 * wn1;
            acc_in[1][0] += xv1 * wn0; acc_in[1][1] += xv1 * wn1;
        }
    }

    // ---- phase 1: h_prev @ w_hh^T ----
    for (int k0 = 0; k0 < HH; k0 += TK) {
        __syncthreads();
        #pragma unroll
        for (int e = tid; e < TB * TK; e += 256) {
            const int b = e >> 4, k = e & 15;
            Xs[k][b] = Hrow[b][k0 + k];
        }
        #pragma unroll
        for (int e = tid; e < 3 * TH * TK; e += 256) {
            const int g = e >> 9, rem = e & 511;
            const int h = rem >> 4, k = rem & 15;
            Ws[g][k][h] = Wh[((size_t)(g * HH + hh0 + h)) * HH + k0 + k];
        }
        __syncthreads();
        #pragma unroll
        for (int kk = 0; kk < TK; ++kk) {
            const float xv0 = Xs[kk][ty];
            const float xv1 = Xs[kk][ty + 16];
            const float wr0 = Ws[0][kk][tx], wr1 = Ws[0][kk][tx + 16];
            const float wz0 = Ws[1][kk][tx], wz1 = Ws[1][kk][tx + 16];
            const float wn0 = Ws[2][kk][tx], wn1 = Ws[2][kk][tx + 16];
            acc_r[0][0]  += xv0 * wr0; acc_r[0][1]  += xv0 * wr1;
            acc_r[1][0]  += xv1 * wr0; acc_r[1][1]  += xv1 * wr1;
            acc_z[0][0]  += xv0 * wz0; acc_z[0][1]  += xv0 * wz1;
            acc_z[1][0]  += xv1 * wz0; acc_z[1][1]  += xv1 * wz1;
            acc_hn[0][0] += xv0 * wn0; acc_hn[0][1] += xv0 * wn1;
            acc_hn[1][0] += xv1 * wn0; acc_hn[1][1] += xv1 * wn1;
        }
    }

    // ---- epilogue: gate math + state update ----
    const float* bi = b_ih + (size_t)layer * 3 * HH;
    const float* bh = b_hh + (size_t)layer * 3 * HH;
    #pragma unroll
    for (int i = 0; i < 2; ++i) {
        const int bl = ty + 16 * i;
        const int b  = bb0 + bl;
        #pragma unroll
        for (int j = 0; j < 2; ++j) {
            const int h = hh0 + tx + 16 * j;
            const float r = sigmoidf_(acc_r[i][j] + bi[h] + bh[h]);
            const float z = sigmoidf_(acc_z[i][j] + bi[HH + h] + bh[HH + h]);
            const float n = tanhf(acc_in[i][j] + bi[2 * HH + h]
                                  + r * (acc_hn[i][j] + bh[2 * HH + h]));
            const float hp = Hrow[bl][h];
            out[((size_t)(t * LL + layer) * BB + b) * HH + h] =
                (1.0f - z) * n + z * hp;
        }
    }
}

__global__ __launch_bounds__(256) void copy_final(
    const float* __restrict__ states, float* __restrict__ dst)
{
    const int i = blockIdx.x * 256 + threadIdx.x;   // L*B*H = 524288 elems
    dst[i] = states[(size_t)(TT - 1) * LL * BB * HH + i];
}

extern "C" void kernel_launch(void* const* d_in, const int* in_sizes, int n_in,
                              void* d_out, int out_size, void* d_ws, size_t ws_size,
                              hipStream_t stream) {
    const int*   input = (const int*)  d_in[0];
    const float* h0    = (const float*)d_in[1];
    const float* emb   = (const float*)d_in[2];
    const float* w_ih  = (const float*)d_in[3];
    const float* w_hh  = (const float*)d_in[4];
    const float* b_ih  = (const float*)d_in[5];
    const float* b_hh  = (const float*)d_in[6];
    float* out = (float*)d_out;

    dim3 grid(BB / TB, HH / TH);   // 16 x 16 = 256 blocks
    for (int t = 0; t < TT; ++t) {
        gru_step<<<grid, 256, 0, stream>>>(input, emb, h0, w_ih, w_hh, b_ih, b_hh, out, 0, t);
        gru_step<<<grid, 256, 0, stream>>>(input, emb, h0, w_ih, w_hh, b_ih, b_hh, out, 1, t);
    }
    copy_final<<<(LL * BB * HH) / 256, 256, 0, stream>>>(out, out + (size_t)TT * LL * BB * HH);
}

// Round 2
// 3181.858 us; speedup vs baseline: 9.5940x; 9.5940x over previous
//
#include <hip/hip_runtime.h>
#include <hip/hip_bf16.h>
#include <math.h>

// GRU encoder: B=512, T=128, V=128, E=512, H=512, L=2
// d_out: states[T][L][B][H] f32, then h_final[L][B][H] f32.
//
// Round 2: bf16-MFMA per-step kernel.
//  - weights/emb/h0 pre-converted to bf16 in ws (once per call).
//  - per (layer,t) launch: grid 8x32=256 blocks, 256 thr = 4 waves.
//    tile: 64 batch x 16 h x 3 gates, K=512 per phase.
//    wave 0/1 = x-phase (x @ Wi^T, K halves), wave 2/3 = h-phase (h @ Wh^T).
//    Fragments loaded global->VGPR directly (A and B lane layouts are
//    16B-contiguous in K); LDS only for cross-wave reduce + gate epilogue.
//  - h carried f32 in d_out; bf16 shadow ping-pongs in ws (no intra-kernel
//    read/write race: step t reads slot (t+1)&1, writes slot t&1).

#define BB 512
#define TT 128
#define VV 128
#define EE 512
#define HH 512
#define LL 2

typedef short s16x8 __attribute__((ext_vector_type(8)));
typedef float f32x4 __attribute__((ext_vector_type(4)));

// ws layout in bf16 elements
#define WI_OFF  0
#define WI_SZ   (LL * 3 * HH * EE)        // 1572864
#define WH_OFF  (WI_OFF + WI_SZ)
#define WH_SZ   (LL * 3 * HH * HH)        // 1572864
#define EMB_OFF (WH_OFF + WH_SZ)
#define EMB_SZ  (VV * EE)                 // 65536
#define HBF_OFF (EMB_OFF + EMB_SZ)
#define HBF_SZ  (LL * 2 * BB * HH)        // 1048576 (ping-pong)
// total 4259840 bf16 = ~8.5 MB

__global__ __launch_bounds__(256) void f32_to_bf16(
    const float* __restrict__ src, __hip_bfloat16* __restrict__ dst, int n)
{
    int i = blockIdx.x * 256 + threadIdx.x;
    if (i < n) dst[i] = __float2bfloat16(src[i]);
}

__global__ __launch_bounds__(256) void gru_step(
    const int*   __restrict__ input,   // [B,T]
    const float* __restrict__ h0,      // [L,B,H] f32
    const float* __restrict__ b_ih,    // [L,3H]
    const float* __restrict__ b_hh,    // [L,3H]
    const __hip_bfloat16* __restrict__ wibf,  // [L,3H,E]
    const __hip_bfloat16* __restrict__ whbf,  // [L,3H,H]
    const __hip_bfloat16* __restrict__ embbf, // [V,E]
    __hip_bfloat16* __restrict__ hbf,         // [L][2][B][H] ping-pong
    float*       __restrict__ out,            // [T,L,B,H]
    int layer, int t)
{
    const int b0  = blockIdx.x * 64;   // batch tile base
    const int h00 = blockIdx.y * 16;   // hidden tile base
    const int tid  = threadIdx.x;
    const int w    = tid >> 6;         // wave 0..3
    const int lane = tid & 63;
    const int l15  = lane & 15;
    const int kl   = (lane >> 4) * 8;  // k-offset within 32-wide MFMA K

    __shared__ float red[4][64][50];   // [wave][b_loc][n_loc(48)+pad]

    const int rd = (t + 1) & 1;        // ping-pong read slot (h_{t-1})
    const int wr = t & 1;              // write slot (h_t)

    const int phase = w >> 1;          // 0: x @ Wi^T   1: h @ Wh^T
    const int kbase = (w & 1) * 256;   // K half per wave

    // ---- A row pointers (per lane: 4 batch sub-tiles) ----
    const __hip_bfloat16* arow[4];
    if (phase == 0) {
        if (layer == 0) {
            #pragma unroll
            for (int s = 0; s < 4; ++s) {
                const int b = b0 + s * 16 + l15;
                arow[s] = embbf + (size_t)input[b * TT + t] * EE;
            }
        } else {
            // layer-1 input = layer-0 state at same t (written by prev launch)
            #pragma unroll
            for (int s = 0; s < 4; ++s)
                arow[s] = hbf + ((size_t)(0 * 2 + wr) * BB + b0 + s * 16 + l15) * HH;
        }
    } else {
        #pragma unroll
        for (int s = 0; s < 4; ++s)
            arow[s] = hbf + ((size_t)(layer * 2 + rd) * BB + b0 + s * 16 + l15) * HH;
    }

    // ---- B row pointers (weight rows for 3 gates) ----
    const __hip_bfloat16* wbase =
        (phase == 0 ? wibf : whbf) + (size_t)layer * 3 * HH * EE;
    const __hip_bfloat16* brow[3];
    #pragma unroll
    for (int g = 0; g < 3; ++g)
        brow[g] = wbase + (size_t)(g * HH + h00 + l15) * EE;

    f32x4 acc[4][3];
    #pragma unroll
    for (int s = 0; s < 4; ++s)
        #pragma unroll
        for (int g = 0; g < 3; ++g)
            acc[s][g] = (f32x4)(0.f);

    // ---- K loop: 8 iterations of 32 ----
    #pragma unroll
    for (int kk = 0; kk < 256; kk += 32) {
        const int ko = kbase + kk + kl;
        s16x8 bfr[3];
        #pragma unroll
        for (int g = 0; g < 3; ++g)
            bfr[g] = *reinterpret_cast<const s16x8*>(brow[g] + ko);
        #pragma unroll
        for (int s = 0; s < 4; ++s) {
            const s16x8 a = *reinterpret_cast<const s16x8*>(arow[s] + ko);
            #pragma unroll
            for (int g = 0; g < 3; ++g)
                acc[s][g] = __builtin_amdgcn_mfma_f32_16x16x32_bf16(
                    a, bfr[g], acc[s][g], 0, 0, 0);
        }
    }

    // ---- cross-wave reduce via LDS ----
    // C/D layout: lane l, reg r -> D[m=(l>>4)*4+r][n=l&15]
    #pragma unroll
    for (int s = 0; s < 4; ++s)
        #pragma unroll
        for (int g = 0; g < 3; ++g)
            #pragma unroll
            for (int r = 0; r < 4; ++r)
                red[w][s * 16 + (lane >> 4) * 4 + r][g * 16 + l15] = acc[s][g][r];
    __syncthreads();

    // ---- fused gate epilogue: 4 (b,h) outputs per thread ----
    const int hl = tid & 15;
    const int bb = tid >> 4;           // 0..15
    const int hg = h00 + hl;
    const float bir = b_ih[layer * 3 * HH + hg];
    const float biz = b_ih[layer * 3 * HH + HH + hg];
    const float bin = b_ih[layer * 3 * HH + 2 * HH + hg];
    const float bhr = b_hh[layer * 3 * HH + hg];
    const float bhz = b_hh[layer * 3 * HH + HH + hg];
    const float bhn = b_hh[layer * 3 * HH + 2 * HH + hg];

    const float* hprev = (t == 0)
        ? (h0 + (size_t)layer * BB * HH)
        : (out + (size_t)((t - 1) * LL + layer) * BB * HH);

    #pragma unroll
    for (int i = 0; i < 4; ++i) {
        const int bl = bb + 16 * i;
        const int bglob = b0 + bl;
        const float sr = red[0][bl][hl] + red[1][bl][hl]
                       + red[2][bl][hl] + red[3][bl][hl];
        const float sz = red[0][bl][16 + hl] + red[1][bl][16 + hl]
                       + red[2][bl][16 + hl] + red[3][bl][16 + hl];
        const float in_ = red[0][bl][32 + hl] + red[1][bl][32 + hl];
        const float hn_ = red[2][bl][32 + hl] + red[3][bl][32 + hl];
        const float r = 1.f / (1.f + __expf(-(sr + bir + bhr)));
        const float z = 1.f / (1.f + __expf(-(sz + biz + bhz)));
        const float n = tanhf(in_ + bin + r * (hn_ + bhn));
        const float hp = hprev[(size_t)bglob * HH + hg];
        const float hnew = (1.f - z) * n + z * hp;
        out[((size_t)(t * LL + layer) * BB + bglob) * HH + hg] = hnew;
        hbf[((size_t)(layer * 2 + wr) * BB + bglob) * HH + hg] =
            __float2bfloat16(hnew);
    }
}

__global__ __launch_bounds__(256) void copy_final(
    const float* __restrict__ states, float* __restrict__ dst)
{
    const int i = blockIdx.x * 256 + threadIdx.x;   // L*B*H
    dst[i] = states[(size_t)(TT - 1) * LL * BB * HH + i];
}

extern "C" void kernel_launch(void* const* d_in, const int* in_sizes, int n_in,
                              void* d_out, int out_size, void* d_ws, size_t ws_size,
                              hipStream_t stream) {
    const int*   input = (const int*)  d_in[0];
    const float* h0    = (const float*)d_in[1];
    const float* emb   = (const float*)d_in[2];
    const float* w_ih  = (const float*)d_in[3];
    const float* w_hh  = (const float*)d_in[4];
    const float* b_ih  = (const float*)d_in[5];
    const float* b_hh  = (const float*)d_in[6];
    float* out = (float*)d_out;

    __hip_bfloat16* ws = (__hip_bfloat16*)d_ws;
    __hip_bfloat16* wibf  = ws + WI_OFF;
    __hip_bfloat16* whbf  = ws + WH_OFF;
    __hip_bfloat16* embbf = ws + EMB_OFF;
    __hip_bfloat16* hbf   = ws + HBF_OFF;

    // pre-convert weights / emb / h0 to bf16
    f32_to_bf16<<<(WI_SZ + 255) / 256, 256, 0, stream>>>(w_ih, wibf, WI_SZ);
    f32_to_bf16<<<(WH_SZ + 255) / 256, 256, 0, stream>>>(w_hh, whbf, WH_SZ);
    f32_to_bf16<<<(EMB_SZ + 255) / 256, 256, 0, stream>>>(emb, embbf, EMB_SZ);
    // h0 -> read slot for t=0, i.e. slot (0+1)&1 = 1, per layer
    f32_to_bf16<<<(BB * HH + 255) / 256, 256, 0, stream>>>(
        h0, hbf + (size_t)(0 * 2 + 1) * BB * HH, BB * HH);
    f32_to_bf16<<<(BB * HH + 255) / 256, 256, 0, stream>>>(
        h0 + (size_t)BB * HH, hbf + (size_t)(1 * 2 + 1) * BB * HH, BB * HH);

    dim3 grid(BB / 64, HH / 16);   // 8 x 32 = 256 blocks
    for (int t = 0; t < TT; ++t) {
        gru_step<<<grid, 256, 0, stream>>>(input, h0, b_ih, b_hh,
                                           wibf, whbf, embbf, hbf, out, 0, t);
        gru_step<<<grid, 256, 0, stream>>>(input, h0, b_ih, b_hh,
                                           wibf, whbf, embbf, hbf, out, 1, t);
    }
    copy_final<<<(LL * BB * HH) / 256, 256, 0, stream>>>(
        out, out + (size_t)TT * LL * BB * HH);
}